// Round 1
// baseline (2044.557 us; speedup 1.0000x reference)
//
#include <hip/hip_runtime.h>
#include <hip/hip_bf16.h>

typedef float f32x4 __attribute__((ext_vector_type(4)));
typedef short s16x8 __attribute__((ext_vector_type(8)));
typedef unsigned short u16;

#define BT 16        // batch rows per workgroup
#define NWG 64       // 1024 / 16
#define H 128
#define VW 256
#define NI 64
#define NSTEPS 64

// ws layout (u16 units): bf16-packed weight tiles.
// Tile layout: [(kk*NT + nt)*64 + lane]*8 + j  ->  B[k = kk*32 + (lane>>4)*8 + j][col = nt*16 + (lane&15)]
#define OFF_W1L 0          // GEMM1: KK=4,  NT=16 -> 32768
#define OFF_W2L 32768      // GEMM2: KK=8,  NT=16 -> 65536
#define OFF_WML 98304      // GEMM3: KK=169, NT=8 -> 692224 (kk 0..167: Wm; kk 168: bm bias block)
#define WS_TOTAL 790528

#define MFMA(a, b, c) __builtin_amdgcn_mfma_f32_16x16x32_bf16(a, b, c, 0, 0, 0)

__device__ __forceinline__ u16 bf16u(float f) {
  union { float f; unsigned u; } x; x.f = f;
  return (u16)((x.u + 0x7fffu + ((x.u >> 16) & 1u)) >> 16);  // RNE
}

__global__ void prep_weights(const float* __restrict__ Wvf1,
                             const float* __restrict__ Wvf2,
                             const float* __restrict__ Wm,
                             const float* __restrict__ bmv,
                             u16* __restrict__ ws) {
  int idx = blockIdx.x * blockDim.x + threadIdx.x;
  if (idx >= WS_TOTAL) return;
  float val;
  if (idx < OFF_W2L) {
    int e = idx;
    int j = e & 7, ln = (e >> 3) & 63, nt = (e >> 9) & 15, kk = e >> 13;
    int cc = ln & 15, kgg = ln >> 4;
    val = Wvf1[(nt * 16 + cc) * H + kk * 32 + kgg * 8 + j];       // B[k=h][col=w] = W_vf1[w][h]
  } else if (idx < OFF_WML) {
    int e = idx - OFF_W2L;
    int j = e & 7, ln = (e >> 3) & 63, nt = (e >> 9) & 15, kk = e >> 13;
    int cc = ln & 15, kgg = ln >> 4;
    val = Wvf2[(nt * 16 + cc) * VW + kk * 32 + kgg * 8 + j];      // B[k=w][col=v] = W_vf2[v][w]
  } else {
    int e = idx - OFF_WML;
    int j = e & 7, ln = (e >> 3) & 63, nt = (e >> 9) & 7, kkg = e >> 12;
    int cc = ln & 15, kgg = ln >> 4;
    int h = nt * 16 + cc;
    if (kkg < 168) {
      int l = kkg >> 3;                       // 8 K-steps of 32 per l (VW=256)
      int w = (kkg & 7) * 32 + kgg * 8 + j;
      val = Wm[(size_t)(h * 21 + l) * VW + w]; // Wm viewed (128,21,256)
    } else {
      int m = kgg * 8 + j;                    // bias block: A will be ls itself
      val = (m < 21) ? bmv[h * 21 + m] : 0.f;
    }
  }
  ws[idx] = bf16u(val);
}

__global__ __launch_bounds__(512, 2) void rde_main(
    const float* __restrict__ logsig, const float* __restrict__ x0,
    const float* __restrict__ W1, const float* __restrict__ b1,
    const float* __restrict__ bvf1, const float* __restrict__ bvf2,
    const float* __restrict__ W2, const float* __restrict__ b2,
    const u16* __restrict__ ws, float* __restrict__ out) {
  // all strides padded to odd multiples of 16B -> 2-way (free) LDS bank aliasing on b128 reads
  __shared__ __align__(16) u16   YB [BT][H + 8];    // bf16 y (GEMM1 A input)
  __shared__ __align__(16) u16   V1R[BT][VW + 8];   // bf16 relu(v1)
  __shared__ __align__(16) u16   V2B[BT][VW + 8];   // bf16 tanh(v2)
  __shared__ __align__(16) float Y32[BT][H + 4];    // f32 master state
  __shared__ __align__(16) float YP32[BT][H + 4];   // y + 0.5*raw1
  __shared__ __align__(16) float K32[BT][H + 4];    // reduction target for raw
  __shared__ __align__(16) float LSFT[21][BT];      // ls transposed (for lsq b128 broadcast)
  __shared__ __align__(16) u16   LSB[BT][40];       // bf16 ls padded to 32 (bias-block A)
  __shared__ float LG[BT][10];

  const int tid = threadIdx.x;
  const int lane = tid & 63;
  const int wv = tid >> 6;     // 0..7
  const int c = lane & 15;     // A-row / B-col / D-col
  const int kg = lane >> 4;    // k-group; D-row base = kg*4
  const int b0 = blockIdx.x * BT;
  const s16x8* __restrict__ sws = (const s16x8*)ws;
  const f32x4 zf = {0.f, 0.f, 0.f, 0.f};

  // y0 = x0 @ W1^T + b1
  for (int e = tid; e < BT * H; e += 512) {
    int r = e >> 7, h = e & 127;
    float a = b1[h];
#pragma unroll
    for (int d = 0; d < 6; ++d) a += x0[(b0 + r) * 6 + d] * W1[h * 6 + d];
    Y32[r][h] = a;
    YB[r][h] = bf16u(a);
  }
  __syncthreads();

  for (int step = 0; step < NSTEPS; ++step) {
#pragma unroll 1
    for (int sub = 0; sub < 2; ++sub) {
      const int jint = sub ? step : (step > 0 ? step - 1 : 0);  // analytic searchsorted
      {  // stage ls for this interval; zero K32
        int r = tid >> 5, l = tid & 31;
        float v = 0.f;
        if (l < 21) v = logsig[((size_t)(b0 + r) * NI + jint) * 22 + 1 + l];
        LSB[r][l] = bf16u(v);
        if (l < 21) LSFT[l][r] = v;
      }
      for (int e = tid; e < BT * H; e += 512) K32[e >> 7][e & 127] = 0.f;

      // ---- GEMM1: v1 = relu(y @ W_vf1^T + b_vf1); wave handles n-tiles {2wv, 2wv+1}
      {
        f32x4 acc0 = zf, acc1 = zf;
#pragma unroll
        for (int kk = 0; kk < 4; ++kk) {
          s16x8 a = *(const s16x8*)&YB[c][kk * 32 + kg * 8];
          s16x8 bA = sws[(kk * 16 + wv * 2 + 0) * 64 + lane];
          s16x8 bB = sws[(kk * 16 + wv * 2 + 1) * 64 + lane];
          acc0 = MFMA(a, bA, acc0);
          acc1 = MFMA(a, bB, acc1);
        }
        int col = wv * 32 + c;
        float bb = bvf1[col];
#pragma unroll
        for (int q = 0; q < 4; ++q) V1R[kg * 4 + q][col] = bf16u(fmaxf(acc0[q] + bb, 0.f));
        col += 16; bb = bvf1[col];
#pragma unroll
        for (int q = 0; q < 4; ++q) V1R[kg * 4 + q][col] = bf16u(fmaxf(acc1[q] + bb, 0.f));
      }
      __syncthreads();

      // ---- GEMM2: v2 = tanh(v1r @ W_vf2^T + b_vf2)
      {
        f32x4 acc0 = zf, acc1 = zf;
#pragma unroll
        for (int kk = 0; kk < 8; ++kk) {
          s16x8 a = *(const s16x8*)&V1R[c][kk * 32 + kg * 8];
          s16x8 bA = sws[OFF_W2L / 8 + (kk * 16 + wv * 2 + 0) * 64 + lane];
          s16x8 bB = sws[OFF_W2L / 8 + (kk * 16 + wv * 2 + 1) * 64 + lane];
          acc0 = MFMA(a, bA, acc0);
          acc1 = MFMA(a, bB, acc1);
        }
        int col = wv * 32 + c;
        float bb = bvf2[col];
#pragma unroll
        for (int q = 0; q < 4; ++q) V2B[kg * 4 + q][col] = bf16u(tanhf(acc0[q] + bb));
        col += 16; bb = bvf2[col];
#pragma unroll
        for (int q = 0; q < 4; ++q) V2B[kg * 4 + q][col] = bf16u(tanhf(acc1[q] + bb));
      }
      __syncthreads();

      // ---- GEMM3: raw[b,h] = sum_l ls[b,l]*(v2[b,:] . Wm[h,l,:]) + sum_l ls[b,l]*bm[h*21+l]
      // waves: half = K-half of VW (w-range), qd -> n-tile pair {2qd, 2qd+1}
      {
        const int half = wv >> 2;
        const int qd = wv & 3;
        s16x8 aK0 = *(const s16x8*)&V2B[c][half * 128 + 0 * 32 + kg * 8];
        s16x8 aK1 = *(const s16x8*)&V2B[c][half * 128 + 1 * 32 + kg * 8];
        s16x8 aK2 = *(const s16x8*)&V2B[c][half * 128 + 2 * 32 + kg * 8];
        s16x8 aK3 = *(const s16x8*)&V2B[c][half * 128 + 3 * 32 + kg * 8];
        f32x4 acc0 = zf, acc1 = zf;
        const int baseW = OFF_WML / 8;
        for (int l = 0; l < 21; ++l) {
          f32x4 lsq = *(const f32x4*)&LSFT[l][kg * 4];
          int kb = baseW + ((l * 8 + half * 4) * 8 + qd * 2) * 64 + lane;
          f32x4 P0 = zf, P1 = zf;
          P0 = MFMA(aK0, sws[kb + 0 * 512], P0);
          P1 = MFMA(aK0, sws[kb + 0 * 512 + 64], P1);
          P0 = MFMA(aK1, sws[kb + 1 * 512], P0);
          P1 = MFMA(aK1, sws[kb + 1 * 512 + 64], P1);
          P0 = MFMA(aK2, sws[kb + 2 * 512], P0);
          P1 = MFMA(aK2, sws[kb + 2 * 512 + 64], P1);
          P0 = MFMA(aK3, sws[kb + 3 * 512], P0);
          P1 = MFMA(aK3, sws[kb + 3 * 512 + 64], P1);
#pragma unroll
          for (int q = 0; q < 4; ++q) {
            acc0[q] += lsq[q] * P0[q];
            acc1[q] += lsq[q] * P1[q];
          }
        }
        if (half == 0) {  // bias block (K-step 168): A = ls (bf16), B = bm tiles
          s16x8 a = *(const s16x8*)&LSB[c][kg * 8];
          int kb = baseW + (168 * 8 + qd * 2) * 64 + lane;
          f32x4 P0 = MFMA(a, sws[kb], zf);
          f32x4 P1 = MFMA(a, sws[kb + 64], zf);
#pragma unroll
          for (int q = 0; q < 4; ++q) { acc0[q] += P0[q]; acc1[q] += P1[q]; }
        }
        int col = qd * 32 + c;
#pragma unroll
        for (int q = 0; q < 4; ++q) atomicAdd(&K32[kg * 4 + q][col], acc0[q]);
        col += 16;
#pragma unroll
        for (int q = 0; q < 4; ++q) atomicAdd(&K32[kg * 4 + q][col], acc1[q]);
      }
      __syncthreads();

      // ---- Heun update (dt/width == 1 exactly)
      if (sub == 0) {
        for (int e = tid; e < BT * H; e += 512) {
          int r = e >> 7, h = e & 127;
          float raw = K32[r][h], y = Y32[r][h];
          YP32[r][h] = y + 0.5f * raw;
          YB[r][h] = bf16u(y + raw);      // y_tmp for k2
        }
      } else {
        for (int e = tid; e < BT * H; e += 512) {
          int r = e >> 7, h = e & 127;
          float yn = YP32[r][h] + 0.5f * K32[r][h];
          Y32[r][h] = yn;
          YB[r][h] = bf16u(yn);
        }
      }
      __syncthreads();
    }
  }

  // ---- logits + softmax (f32)
  if (tid < 160) {
    int r = tid / 10, cc = tid % 10;
    float a = b2[cc];
    for (int h = 0; h < H; ++h) a += Y32[r][h] * W2[cc * H + h];
    LG[r][cc] = a;
  }
  __syncthreads();
  if (tid < 16) {
    float m = -1e30f;
#pragma unroll
    for (int cc = 0; cc < 10; ++cc) m = fmaxf(m, LG[tid][cc]);
    float ex[10]; float s = 0.f;
#pragma unroll
    for (int cc = 0; cc < 10; ++cc) { ex[cc] = expf(LG[tid][cc] - m); s += ex[cc]; }
    float inv = 1.f / s;
#pragma unroll
    for (int cc = 0; cc < 10; ++cc) out[(b0 + tid) * 10 + cc] = ex[cc] * inv;
  }
}

extern "C" void kernel_launch(void* const* d_in, const int* in_sizes, int n_in,
                              void* d_out, int out_size, void* d_ws, size_t ws_size,
                              hipStream_t stream) {
  (void)in_sizes; (void)n_in; (void)out_size; (void)ws_size;
  const float* logsig = (const float*)d_in[1];
  const float* x0     = (const float*)d_in[2];
  const float* Wvf1   = (const float*)d_in[3];
  const float* bvf1   = (const float*)d_in[4];
  const float* Wvf2   = (const float*)d_in[5];
  const float* bvf2   = (const float*)d_in[6];
  const float* Wm     = (const float*)d_in[7];
  const float* bmv    = (const float*)d_in[8];
  const float* W1     = (const float*)d_in[9];
  const float* b1     = (const float*)d_in[10];
  const float* W2     = (const float*)d_in[11];
  const float* b2     = (const float*)d_in[12];
  u16* ws = (u16*)d_ws;

  prep_weights<<<(WS_TOTAL + 255) / 256, 256, 0, stream>>>(Wvf1, Wvf2, Wm, bmv, ws);
  rde_main<<<NWG, 512, 0, stream>>>(logsig, x0, W1, b1, bvf1, bvf2, W2, b2, ws,
                                    (float*)d_out);
}

// Round 2
// 1341.663 us; speedup vs baseline: 1.5239x; 1.5239x over previous
//
#include <hip/hip_runtime.h>
#include <hip/hip_bf16.h>

typedef float f32x4 __attribute__((ext_vector_type(4)));
typedef short s16x8 __attribute__((ext_vector_type(8)));
typedef unsigned short u16;

#define BT 16        // batch rows per workgroup
#define NWG 64       // 1024 / 16
#define H 128
#define VW 256
#define NI 64
#define NSTEPS 64

// ws layout (u16 units): bf16-packed weight tiles.
// Fragment layout: [(kk*NT + nt)*64 + lane]*8 + j -> B[k = kk*32 + (lane>>4)*8 + j][col = nt*16 + (lane&15)]
#define OFF_W1L 0          // GEMM1: KK=4,  NT=16 -> 32768 u16
#define OFF_W2L 32768      // GEMM2: KK=8,  NT=16 -> 65536 u16
#define OFF_WML 98304      // GEMM3: KK=169, NT=8 -> 692224 u16 (kk 168 = bm bias block)
#define WS_TOTAL 790528

#define MFMA(a, b, c) __builtin_amdgcn_mfma_f32_16x16x32_bf16(a, b, c, 0, 0, 0)

__device__ __forceinline__ u16 bf16u(float f) {
  union { float f; unsigned u; } x; x.f = f;
  return (u16)((x.u + 0x7fffu + ((x.u >> 16) & 1u)) >> 16);  // RNE
}

__device__ __forceinline__ float tanh_fast(float x) {
  float e = __expf(2.f * x);                       // v_exp_f32 path; inf/0 saturate correctly
  return 1.f - 2.f * __builtin_amdgcn_rcpf(e + 1.f);
}

__global__ void prep_weights(const float* __restrict__ Wvf1,
                             const float* __restrict__ Wvf2,
                             const float* __restrict__ Wm,
                             const float* __restrict__ bmv,
                             u16* __restrict__ ws) {
  int idx = blockIdx.x * blockDim.x + threadIdx.x;
  if (idx >= WS_TOTAL) return;
  float val;
  if (idx < OFF_W2L) {
    int e = idx;
    int j = e & 7, ln = (e >> 3) & 63, nt = (e >> 9) & 15, kk = e >> 13;
    int cc = ln & 15, kgg = ln >> 4;
    val = Wvf1[(nt * 16 + cc) * H + kk * 32 + kgg * 8 + j];
  } else if (idx < OFF_WML) {
    int e = idx - OFF_W2L;
    int j = e & 7, ln = (e >> 3) & 63, nt = (e >> 9) & 15, kk = e >> 13;
    int cc = ln & 15, kgg = ln >> 4;
    val = Wvf2[(nt * 16 + cc) * VW + kk * 32 + kgg * 8 + j];
  } else {
    int e = idx - OFF_WML;
    int j = e & 7, ln = (e >> 3) & 63, nt = (e >> 9) & 7, kkg = e >> 12;
    int cc = ln & 15, kgg = ln >> 4;
    int h = nt * 16 + cc;
    if (kkg < 168) {
      int l = kkg >> 3;
      int w = (kkg & 7) * 32 + kgg * 8 + j;
      val = Wm[(size_t)(h * 21 + l) * VW + w];
    } else {
      int m = kgg * 8 + j;
      val = (m < 21) ? bmv[h * 21 + m] : 0.f;
    }
  }
  ws[idx] = bf16u(val);
}

__global__ __launch_bounds__(512, 2) void rde_main(
    const float* __restrict__ logsig, const float* __restrict__ x0,
    const float* __restrict__ W1, const float* __restrict__ b1,
    const float* __restrict__ bvf1, const float* __restrict__ bvf2,
    const float* __restrict__ W2, const float* __restrict__ b2,
    const u16* __restrict__ ws, float* __restrict__ out) {
  __shared__ __align__(16) u16   W1Ls[OFF_W2L];     // GEMM1 weights, fragment-linear (64 KB)
  __shared__ __align__(16) u16   YB [BT][H + 8];    // bf16 y (GEMM1 A)
  __shared__ __align__(16) u16   V1R[BT][VW + 8];   // bf16 relu(v1)
  __shared__ __align__(16) u16   V2B[BT][VW + 8];   // bf16 tanh(v2)
  __shared__ __align__(16) float Y32[BT][H + 4];    // f32 master state
  __shared__ __align__(16) float YP32[BT][H + 4];   // y + 0.5*raw1
  __shared__ __align__(16) float LSF[2][21][BT];    // f32 ls transposed, ping-pong by interval parity
  __shared__ __align__(16) u16   LSB[2][BT][40];    // bf16 ls padded to 32, ping-pong
  __shared__ float LG[BT][10];

  const int tid = threadIdx.x;
  const int lane = tid & 63;
  const int wv = tid >> 6;     // 0..7
  const int c = lane & 15;     // A-row / B-col / D-col
  const int kg = lane >> 4;    // k-group; D-row base = kg*4
  const int b0 = blockIdx.x * BT;
  const s16x8* __restrict__ sws = (const s16x8*)ws;
  const f32x4 zf = {0.f, 0.f, 0.f, 0.f};

  // ---- persistent register-resident weights
  s16x8 w2r[2][8];
#pragma unroll
  for (int t = 0; t < 2; ++t)
#pragma unroll
    for (int kk = 0; kk < 8; ++kk)
      w2r[t][kk] = sws[OFF_W2L / 8 + (kk * 16 + wv * 2 + t) * 64 + lane];
  s16x8 wbias = sws[OFF_WML / 8 + (168 * 8 + wv) * 64 + lane];
  const float bv1a = bvf1[wv * 32 + c], bv1b = bvf1[wv * 32 + 16 + c];
  const float bv2a = bvf2[wv * 32 + c], bv2b = bvf2[wv * 32 + 16 + c];

  // ---- GEMM1 weights -> LDS (fragment-linear copy)
  for (int e = tid; e < OFF_W2L / 8; e += 512)
    ((s16x8*)W1Ls)[e] = sws[e];

  // ---- zero LSB pad region (cols 21..31 stay zero forever)
  for (int e = tid; e < 2 * BT * 40; e += 512) ((u16*)LSB)[e] = 0;

  // ---- y0 = x0 @ W1^T + b1
  for (int e = tid; e < BT * H; e += 512) {
    int r = e >> 7, h = e & 127;
    float a = b1[h];
#pragma unroll
    for (int d = 0; d < 6; ++d) a += x0[(b0 + r) * 6 + d] * W1[h * 6 + d];
    Y32[r][h] = a;
    YB[r][h] = bf16u(a);
  }
  __syncthreads();

  const s16x8* wbase = sws + OFF_WML / 8 + wv * 64 + lane;

#define G3_LOAD(x0v, x1v, x2v, x3v, x4v, x5v, x6v, x7v, L)                     \
  do {                                                                         \
    x0v = wbase[((L) * 8 + 0) * 512]; x1v = wbase[((L) * 8 + 1) * 512];        \
    x2v = wbase[((L) * 8 + 2) * 512]; x3v = wbase[((L) * 8 + 3) * 512];        \
    x4v = wbase[((L) * 8 + 4) * 512]; x5v = wbase[((L) * 8 + 5) * 512];        \
    x6v = wbase[((L) * 8 + 6) * 512]; x7v = wbase[((L) * 8 + 7) * 512];        \
  } while (0)

#define G3_STEP(x0v, x1v, x2v, x3v, x4v, x5v, x6v, x7v, L)                     \
  do {                                                                         \
    f32x4 P0 = MFMA(ag0, x0v, zf); P0 = MFMA(ag1, x1v, P0);                    \
    P0 = MFMA(ag2, x2v, P0);       P0 = MFMA(ag3, x3v, P0);                    \
    f32x4 P1 = MFMA(ag4, x4v, zf); P1 = MFMA(ag5, x5v, P1);                    \
    P1 = MFMA(ag6, x6v, P1);       P1 = MFMA(ag7, x7v, P1);                    \
    f32x4 lsq = *(const f32x4*)&LSF[lsb][(L)][kg * 4];                         \
    _Pragma("unroll")                                                          \
    for (int q = 0; q < 4; ++q) acc[q] += lsq[q] * (P0[q] + P1[q]);            \
  } while (0)

#pragma unroll 1
  for (int step = 0; step < NSTEPS; ++step) {
#pragma unroll 1
    for (int sub = 0; sub < 2; ++sub) {
      const int jint = sub ? step : (step > 0 ? step - 1 : 0);
      const int lsb = jint & 1;

      // stage ls for interval `step` (used by k2 now and k1 of next step)
      if (sub == 0 && tid < BT * 21) {
        int r = tid / 21, l = tid % 21;
        float v = logsig[((size_t)(b0 + r) * NI + step) * 22 + 1 + l];
        LSF[step & 1][l][r] = v;
        LSB[step & 1][r][l] = bf16u(v);
      }

      // ---- GEMM1: v1 = relu(y @ W_vf1^T + b_vf1); B from LDS, 2 n-tiles/wave
      {
        s16x8 ay0 = *(const s16x8*)&YB[c][0 * 32 + kg * 8];
        s16x8 ay1 = *(const s16x8*)&YB[c][1 * 32 + kg * 8];
        s16x8 ay2 = *(const s16x8*)&YB[c][2 * 32 + kg * 8];
        s16x8 ay3 = *(const s16x8*)&YB[c][3 * 32 + kg * 8];
        f32x4 p0 = zf, p1 = zf;
#pragma unroll
        for (int kk = 0; kk < 4; ++kk) {
          s16x8 bA = *(const s16x8*)&W1Ls[((kk * 16 + wv * 2 + 0) * 64 + lane) * 8];
          s16x8 bB = *(const s16x8*)&W1Ls[((kk * 16 + wv * 2 + 1) * 64 + lane) * 8];
          s16x8 a = (kk == 0) ? ay0 : (kk == 1) ? ay1 : (kk == 2) ? ay2 : ay3;
          p0 = MFMA(a, bA, p0);
          p1 = MFMA(a, bB, p1);
        }
        int col = wv * 32 + c;
#pragma unroll
        for (int q = 0; q < 4; ++q) V1R[kg * 4 + q][col] = bf16u(fmaxf(p0[q] + bv1a, 0.f));
#pragma unroll
        for (int q = 0; q < 4; ++q) V1R[kg * 4 + q][col + 16] = bf16u(fmaxf(p1[q] + bv1b, 0.f));
      }
      __syncthreads();

      // ---- GEMM2: v2 = tanh(v1 @ W_vf2^T + b_vf2); B in VGPRs
      {
        s16x8 av0 = *(const s16x8*)&V1R[c][0 * 32 + kg * 8];
        s16x8 av1 = *(const s16x8*)&V1R[c][1 * 32 + kg * 8];
        s16x8 av2 = *(const s16x8*)&V1R[c][2 * 32 + kg * 8];
        s16x8 av3 = *(const s16x8*)&V1R[c][3 * 32 + kg * 8];
        s16x8 av4 = *(const s16x8*)&V1R[c][4 * 32 + kg * 8];
        s16x8 av5 = *(const s16x8*)&V1R[c][5 * 32 + kg * 8];
        s16x8 av6 = *(const s16x8*)&V1R[c][6 * 32 + kg * 8];
        s16x8 av7 = *(const s16x8*)&V1R[c][7 * 32 + kg * 8];
        f32x4 p0a = zf, p0b = zf, p1a = zf, p1b = zf;
        p0a = MFMA(av0, w2r[0][0], p0a); p1a = MFMA(av0, w2r[1][0], p1a);
        p0b = MFMA(av4, w2r[0][4], p0b); p1b = MFMA(av4, w2r[1][4], p1b);
        p0a = MFMA(av1, w2r[0][1], p0a); p1a = MFMA(av1, w2r[1][1], p1a);
        p0b = MFMA(av5, w2r[0][5], p0b); p1b = MFMA(av5, w2r[1][5], p1b);
        p0a = MFMA(av2, w2r[0][2], p0a); p1a = MFMA(av2, w2r[1][2], p1a);
        p0b = MFMA(av6, w2r[0][6], p0b); p1b = MFMA(av6, w2r[1][6], p1b);
        p0a = MFMA(av3, w2r[0][3], p0a); p1a = MFMA(av3, w2r[1][3], p1a);
        p0b = MFMA(av7, w2r[0][7], p0b); p1b = MFMA(av7, w2r[1][7], p1b);
        int col = wv * 32 + c;
#pragma unroll
        for (int q = 0; q < 4; ++q) V2B[kg * 4 + q][col] = bf16u(tanh_fast(p0a[q] + p0b[q] + bv2a));
#pragma unroll
        for (int q = 0; q < 4; ++q) V2B[kg * 4 + q][col + 16] = bf16u(tanh_fast(p1a[q] + p1b[q] + bv2b));
      }
      __syncthreads();

      // ---- GEMM3: wave = n-tile wv, full K; software-pipelined l-loop
      {
        s16x8 ag0 = *(const s16x8*)&V2B[c][0 * 32 + kg * 8];
        s16x8 ag1 = *(const s16x8*)&V2B[c][1 * 32 + kg * 8];
        s16x8 ag2 = *(const s16x8*)&V2B[c][2 * 32 + kg * 8];
        s16x8 ag3 = *(const s16x8*)&V2B[c][3 * 32 + kg * 8];
        s16x8 ag4 = *(const s16x8*)&V2B[c][4 * 32 + kg * 8];
        s16x8 ag5 = *(const s16x8*)&V2B[c][5 * 32 + kg * 8];
        s16x8 ag6 = *(const s16x8*)&V2B[c][6 * 32 + kg * 8];
        s16x8 ag7 = *(const s16x8*)&V2B[c][7 * 32 + kg * 8];
        f32x4 acc = zf;
        s16x8 xa0, xa1, xa2, xa3, xa4, xa5, xa6, xa7;
        s16x8 xb0, xb1, xb2, xb3, xb4, xb5, xb6, xb7;
        G3_LOAD(xa0, xa1, xa2, xa3, xa4, xa5, xa6, xa7, 0);
#pragma unroll 1
        for (int l = 0; l < 20; l += 2) {
          G3_LOAD(xb0, xb1, xb2, xb3, xb4, xb5, xb6, xb7, l + 1);
          G3_STEP(xa0, xa1, xa2, xa3, xa4, xa5, xa6, xa7, l);
          G3_LOAD(xa0, xa1, xa2, xa3, xa4, xa5, xa6, xa7, l + 2);
          G3_STEP(xb0, xb1, xb2, xb3, xb4, xb5, xb6, xb7, l + 1);
        }
        G3_STEP(xa0, xa1, xa2, xa3, xa4, xa5, xa6, xa7, 20);
        // bias block: A = ls (bf16, zero-padded to K=32), B = bm tile
        {
          s16x8 als = *(const s16x8*)&LSB[lsb][c][kg * 8];
          f32x4 Pb = MFMA(als, wbias, zf);
#pragma unroll
          for (int q = 0; q < 4; ++q) acc[q] += Pb[q];
        }
        // ---- fused Heun epilogue (wave-local h-block: h = wv*16 + c)
        int h = wv * 16 + c;
        if (sub == 0) {
#pragma unroll
          for (int q = 0; q < 4; ++q) {
            int r = kg * 4 + q;
            float y = Y32[r][h], raw = acc[q];
            YP32[r][h] = y + 0.5f * raw;
            YB[r][h] = bf16u(y + raw);
          }
        } else {
#pragma unroll
          for (int q = 0; q < 4; ++q) {
            int r = kg * 4 + q;
            float yn = YP32[r][h] + 0.5f * acc[q];
            Y32[r][h] = yn;
            YB[r][h] = bf16u(yn);
          }
        }
      }
      __syncthreads();
    }
  }

  // ---- logits + softmax (f32, once)
  if (tid < 160) {
    int r = tid / 10, cc = tid % 10;
    float a = b2[cc];
#pragma unroll 4
    for (int h = 0; h < H; ++h) a += Y32[r][h] * W2[cc * H + h];
    LG[r][cc] = a;
  }
  __syncthreads();
  if (tid < 16) {
    float m = -1e30f;
#pragma unroll
    for (int cc = 0; cc < 10; ++cc) m = fmaxf(m, LG[tid][cc]);
    float ex[10]; float s = 0.f;
#pragma unroll
    for (int cc = 0; cc < 10; ++cc) { ex[cc] = expf(LG[tid][cc] - m); s += ex[cc]; }
    float inv = 1.f / s;
#pragma unroll
    for (int cc = 0; cc < 10; ++cc) out[(b0 + tid) * 10 + cc] = ex[cc] * inv;
  }
}

extern "C" void kernel_launch(void* const* d_in, const int* in_sizes, int n_in,
                              void* d_out, int out_size, void* d_ws, size_t ws_size,
                              hipStream_t stream) {
  (void)in_sizes; (void)n_in; (void)out_size; (void)ws_size;
  const float* logsig = (const float*)d_in[1];
  const float* x0     = (const float*)d_in[2];
  const float* Wvf1   = (const float*)d_in[3];
  const float* bvf1   = (const float*)d_in[4];
  const float* Wvf2   = (const float*)d_in[5];
  const float* bvf2   = (const float*)d_in[6];
  const float* Wm     = (const float*)d_in[7];
  const float* bmv    = (const float*)d_in[8];
  const float* W1     = (const float*)d_in[9];
  const float* b1     = (const float*)d_in[10];
  const float* W2     = (const float*)d_in[11];
  const float* b2     = (const float*)d_in[12];
  u16* ws = (u16*)d_ws;

  prep_weights<<<(WS_TOTAL + 255) / 256, 256, 0, stream>>>(Wvf1, Wvf2, Wm, bmv, ws);
  rde_main<<<NWG, 512, 0, stream>>>(logsig, x0, W1, b1, bvf1, bvf2, W2, b2, ws,
                                    (float*)d_out);
}

// Round 3
// 991.604 us; speedup vs baseline: 2.0619x; 1.3530x over previous
//
#include <hip/hip_runtime.h>
#include <hip/hip_bf16.h>

typedef float f32x4 __attribute__((ext_vector_type(4)));
typedef short s16x8 __attribute__((ext_vector_type(8)));
typedef unsigned short u16;

#define BT 16        // batch rows per group
#define NWG 256      // 64 groups x 4 WGs (h-split)
#define H 128
#define VW 256
#define NI 64
#define NSTEPS 64

// ws layout (u16 units): bf16-packed weight tiles.
// Fragment layout: [(kk*NT + nt)*64 + lane]*8 + j -> B[k = kk*32 + (lane>>4)*8 + j][col = nt*16 + (lane&15)]
#define OFF_W1L 0          // GEMM1: KK=4,  NT=16 -> 32768 u16
#define OFF_W2L 32768      // GEMM2: KK=8,  NT=16 -> 65536 u16
#define OFF_WML 98304      // GEMM3: KK=169, NT=8 -> 692224 u16 (kk 168 = bm bias block)
#define WS_TOTAL 790528
// byte offsets past weights: ctr (64 groups x 64B = 4KB), ybuf u32[2][64][4][256] = 512KB

#define MFMA(a, b, c) __builtin_amdgcn_mfma_f32_16x16x32_bf16(a, b, c, 0, 0, 0)

__device__ __forceinline__ u16 bf16u(float f) {
  union { float f; unsigned u; } x; x.f = f;
  return (u16)((x.u + 0x7fffu + ((x.u >> 16) & 1u)) >> 16);  // RNE
}
__device__ __forceinline__ float b2f(u16 u) {
  union { unsigned u; float f; } x; x.u = ((unsigned)u) << 16;
  return x.f;
}
__device__ __forceinline__ float tanh_fast(float x) {
  float e = __expf(2.f * x);
  return 1.f - 2.f * __builtin_amdgcn_rcpf(e + 1.f);
}

__global__ void prep_weights(const float* __restrict__ Wvf1,
                             const float* __restrict__ Wvf2,
                             const float* __restrict__ Wm,
                             const float* __restrict__ bmv,
                             u16* __restrict__ ws) {
  int idx = blockIdx.x * blockDim.x + threadIdx.x;
  if (idx < 1024) ((unsigned*)(ws + WS_TOTAL))[idx] = 0u;  // zero sync counters each call
  if (idx >= WS_TOTAL) return;
  float val;
  if (idx < OFF_W2L) {
    int e = idx;
    int j = e & 7, ln = (e >> 3) & 63, nt = (e >> 9) & 15, kk = e >> 13;
    int cc = ln & 15, kgg = ln >> 4;
    val = Wvf1[(nt * 16 + cc) * H + kk * 32 + kgg * 8 + j];
  } else if (idx < OFF_WML) {
    int e = idx - OFF_W2L;
    int j = e & 7, ln = (e >> 3) & 63, nt = (e >> 9) & 15, kk = e >> 13;
    int cc = ln & 15, kgg = ln >> 4;
    val = Wvf2[(nt * 16 + cc) * VW + kk * 32 + kgg * 8 + j];
  } else {
    int e = idx - OFF_WML;
    int j = e & 7, ln = (e >> 3) & 63, nt = (e >> 9) & 7, kkg = e >> 12;
    int cc = ln & 15, kgg = ln >> 4;
    int h = nt * 16 + cc;
    if (kkg < 168) {
      int l = kkg >> 3;
      int w = (kkg & 7) * 32 + kgg * 8 + j;
      val = Wm[(size_t)(h * 21 + l) * VW + w];
    } else {
      int m = kgg * 8 + j;
      val = (m < 21) ? bmv[h * 21 + m] : 0.f;
    }
  }
  ws[idx] = bf16u(val);
}

__global__ __launch_bounds__(512, 2) void rde_main(
    const float* __restrict__ logsig, const float* __restrict__ x0,
    const float* __restrict__ W1, const float* __restrict__ b1,
    const float* __restrict__ bvf1, const float* __restrict__ bvf2,
    const float* __restrict__ W2, const float* __restrict__ b2,
    const u16* __restrict__ ws, unsigned* __restrict__ ctr,
    unsigned* __restrict__ ybuf, float* __restrict__ out) {
  __shared__ __align__(16) u16   W1Ls[OFF_W2L];     // GEMM1 weights (64 KB)
  __shared__ __align__(16) u16   YB [BT][H + 8];    // full bf16 y (GEMM1 A)
  __shared__ __align__(16) u16   V1R[BT][VW + 8];   // bf16 relu(v1)
  __shared__ __align__(16) u16   V2B[BT][VW + 8];   // bf16 tanh(v2)
  __shared__ __align__(16) float LSF[2][21][BT];    // f32 ls, ping-pong by interval parity
  __shared__ __align__(16) u16   LSB[2][BT][40];    // bf16 ls padded to 32
  __shared__ __align__(16) float part[4][BT][32];   // GEMM3 l-subset partials
  __shared__ float LG[BT][10];

  const int tid = threadIdx.x;
  const int lane = tid & 63;
  const int wv = tid >> 6;     // 0..7
  const int c = lane & 15;
  const int kg = lane >> 4;

  // group decomposition: bid = x + 8*(gg*4 + t); members of group share XCD (heuristic)
  const int bid = blockIdx.x;
  const int g = (bid & 7) * 8 + ((bid >> 3) >> 2);  // 0..63
  const int t = (bid >> 3) & 3;                     // h-quarter role 0..3
  const int b0 = g * BT;
  unsigned* ctrg = ctr + g * 16;                    // 64B-strided counters

  const s16x8* __restrict__ sws = (const s16x8*)ws;
  const f32x4 zf = {0.f, 0.f, 0.f, 0.f};

  // ---- persistent register weights
  s16x8 w2r[2][8];
#pragma unroll
  for (int t2 = 0; t2 < 2; ++t2)
#pragma unroll
    for (int kk = 0; kk < 8; ++kk)
      w2r[t2][kk] = sws[OFF_W2L / 8 + (kk * 16 + wv * 2 + t2) * 64 + lane];
  const int nt = wv & 1;        // n-tile within quarter
  const int jq = wv >> 1;       // l-subset 0..3
  const int ntg = t * 2 + nt;   // global n-tile 0..7
  s16x8 wbias = sws[OFF_WML / 8 + (168 * 8 + ntg) * 64 + lane];
  const float bv1a = bvf1[wv * 32 + c], bv1b = bvf1[wv * 32 + 16 + c];
  const float bv2a = bvf2[wv * 32 + c], bv2b = bvf2[wv * 32 + 16 + c];

  for (int e = tid; e < OFF_W2L / 8; e += 512) ((s16x8*)W1Ls)[e] = sws[e];
  for (int e = tid; e < 2 * BT * 40; e += 512) ((u16*)LSB)[e] = 0;

  // ---- y0 = x0 @ W1^T + b1 : full bf16 YB (redundant) + own f32 state element
  for (int e = tid; e < BT * H; e += 512) {
    int r = e >> 7, h = e & 127;
    float a = b1[h];
#pragma unroll
    for (int d = 0; d < 6; ++d) a += x0[(b0 + r) * 6 + d] * W1[h * 6 + d];
    YB[r][h] = bf16u(a);
  }
  float y_st, yp_st = 0.f;
  {
    int r = tid >> 5, h = t * 32 + (tid & 31);
    float a = b1[h];
#pragma unroll
    for (int d = 0; d < 6; ++d) a += x0[(b0 + r) * 6 + d] * W1[h * 6 + d];
    y_st = a;
  }
  __syncthreads();

  const s16x8* wb3 = sws + OFF_WML / 8 + ntg * 64 + lane;
  int phase = 0;

#define G3_LOAD(x0v, x1v, x2v, x3v, x4v, x5v, x6v, x7v, L)                     \
  do {                                                                         \
    x0v = wb3[((L) * 8 + 0) * 512]; x1v = wb3[((L) * 8 + 1) * 512];            \
    x2v = wb3[((L) * 8 + 2) * 512]; x3v = wb3[((L) * 8 + 3) * 512];            \
    x4v = wb3[((L) * 8 + 4) * 512]; x5v = wb3[((L) * 8 + 5) * 512];            \
    x6v = wb3[((L) * 8 + 6) * 512]; x7v = wb3[((L) * 8 + 7) * 512];            \
  } while (0)

#define G3_STEP(x0v, x1v, x2v, x3v, x4v, x5v, x6v, x7v, L)                     \
  do {                                                                         \
    f32x4 P0 = MFMA(ag0, x0v, zf); f32x4 P1 = MFMA(ag4, x4v, zf);              \
    P0 = MFMA(ag1, x1v, P0);       P1 = MFMA(ag5, x5v, P1);                    \
    P0 = MFMA(ag2, x2v, P0);       P1 = MFMA(ag6, x6v, P1);                    \
    P0 = MFMA(ag3, x3v, P0);       P1 = MFMA(ag7, x7v, P1);                    \
    f32x4 lsq = *(const f32x4*)&LSF[lsb][(L)][kg * 4];                         \
    _Pragma("unroll")                                                          \
    for (int qq = 0; qq < 4; ++qq) acc[qq] += lsq[qq] * (P0[qq] + P1[qq]);     \
  } while (0)

#pragma unroll 1
  for (int step = 0; step < NSTEPS; ++step) {
#pragma unroll 1
    for (int sub = 0; sub < 2; ++sub) {
      const int jint = sub ? step : (step > 0 ? step - 1 : 0);
      const int lsb = jint & 1;

      if (sub == 0 && tid < BT * 21) {
        int r = tid / 21, l = tid % 21;
        float v = logsig[((size_t)(b0 + r) * NI + step) * 22 + 1 + l];
        LSF[step & 1][l][r] = v;
        LSB[step & 1][r][l] = bf16u(v);
      }

      // ---- GEMM1 (redundant, full width): v1 = relu(y @ W_vf1^T + b_vf1)
      {
        s16x8 ay0 = *(const s16x8*)&YB[c][0 * 32 + kg * 8];
        s16x8 ay1 = *(const s16x8*)&YB[c][1 * 32 + kg * 8];
        s16x8 ay2 = *(const s16x8*)&YB[c][2 * 32 + kg * 8];
        s16x8 ay3 = *(const s16x8*)&YB[c][3 * 32 + kg * 8];
        f32x4 p0 = zf, p1 = zf;
#pragma unroll
        for (int kk = 0; kk < 4; ++kk) {
          s16x8 bA = *(const s16x8*)&W1Ls[((kk * 16 + wv * 2 + 0) * 64 + lane) * 8];
          s16x8 bB = *(const s16x8*)&W1Ls[((kk * 16 + wv * 2 + 1) * 64 + lane) * 8];
          s16x8 a = (kk == 0) ? ay0 : (kk == 1) ? ay1 : (kk == 2) ? ay2 : ay3;
          p0 = MFMA(a, bA, p0);
          p1 = MFMA(a, bB, p1);
        }
        int col = wv * 32 + c;
#pragma unroll
        for (int q = 0; q < 4; ++q) V1R[kg * 4 + q][col] = bf16u(fmaxf(p0[q] + bv1a, 0.f));
#pragma unroll
        for (int q = 0; q < 4; ++q) V1R[kg * 4 + q][col + 16] = bf16u(fmaxf(p1[q] + bv1b, 0.f));
      }
      __syncthreads();

      // ---- GEMM2 (redundant, full width): v2 = tanh(v1 @ W_vf2^T + b_vf2)
      {
        s16x8 av0 = *(const s16x8*)&V1R[c][0 * 32 + kg * 8];
        s16x8 av1 = *(const s16x8*)&V1R[c][1 * 32 + kg * 8];
        s16x8 av2 = *(const s16x8*)&V1R[c][2 * 32 + kg * 8];
        s16x8 av3 = *(const s16x8*)&V1R[c][3 * 32 + kg * 8];
        s16x8 av4 = *(const s16x8*)&V1R[c][4 * 32 + kg * 8];
        s16x8 av5 = *(const s16x8*)&V1R[c][5 * 32 + kg * 8];
        s16x8 av6 = *(const s16x8*)&V1R[c][6 * 32 + kg * 8];
        s16x8 av7 = *(const s16x8*)&V1R[c][7 * 32 + kg * 8];
        f32x4 p0a = zf, p0b = zf, p1a = zf, p1b = zf;
        p0a = MFMA(av0, w2r[0][0], p0a); p1a = MFMA(av0, w2r[1][0], p1a);
        p0b = MFMA(av4, w2r[0][4], p0b); p1b = MFMA(av4, w2r[1][4], p1b);
        p0a = MFMA(av1, w2r[0][1], p0a); p1a = MFMA(av1, w2r[1][1], p1a);
        p0b = MFMA(av5, w2r[0][5], p0b); p1b = MFMA(av5, w2r[1][5], p1b);
        p0a = MFMA(av2, w2r[0][2], p0a); p1a = MFMA(av2, w2r[1][2], p1a);
        p0b = MFMA(av6, w2r[0][6], p0b); p1b = MFMA(av6, w2r[1][6], p1b);
        p0a = MFMA(av3, w2r[0][3], p0a); p1a = MFMA(av3, w2r[1][3], p1a);
        p0b = MFMA(av7, w2r[0][7], p0b); p1b = MFMA(av7, w2r[1][7], p1b);
        int col = wv * 32 + c;
#pragma unroll
        for (int q = 0; q < 4; ++q) V2B[kg * 4 + q][col] = bf16u(tanh_fast(p0a[q] + p0b[q] + bv2a));
#pragma unroll
        for (int q = 0; q < 4; ++q) V2B[kg * 4 + q][col + 16] = bf16u(tanh_fast(p1a[q] + p1b[q] + bv2b));
      }
      __syncthreads();

      // ---- GEMM3 (own h-quarter): wave (nt, jq) does l in {jq, jq+4, ...}
      {
        s16x8 ag0 = *(const s16x8*)&V2B[c][0 * 32 + kg * 8];
        s16x8 ag1 = *(const s16x8*)&V2B[c][1 * 32 + kg * 8];
        s16x8 ag2 = *(const s16x8*)&V2B[c][2 * 32 + kg * 8];
        s16x8 ag3 = *(const s16x8*)&V2B[c][3 * 32 + kg * 8];
        s16x8 ag4 = *(const s16x8*)&V2B[c][4 * 32 + kg * 8];
        s16x8 ag5 = *(const s16x8*)&V2B[c][5 * 32 + kg * 8];
        s16x8 ag6 = *(const s16x8*)&V2B[c][6 * 32 + kg * 8];
        s16x8 ag7 = *(const s16x8*)&V2B[c][7 * 32 + kg * 8];
        f32x4 acc = zf;
        s16x8 xa0, xa1, xa2, xa3, xa4, xa5, xa6, xa7;
        s16x8 xb0, xb1, xb2, xb3, xb4, xb5, xb6, xb7;
        const int nl = (jq == 0) ? 6 : 5;   // l = jq + 4*i ; jq==0 also gets l=20
        G3_LOAD(xa0, xa1, xa2, xa3, xa4, xa5, xa6, xa7, jq);
        int i = 1;
#pragma unroll 1
        for (; i + 1 < nl; i += 2) {
          G3_LOAD(xb0, xb1, xb2, xb3, xb4, xb5, xb6, xb7, jq + 4 * i);
          G3_STEP(xa0, xa1, xa2, xa3, xa4, xa5, xa6, xa7, jq + 4 * (i - 1));
          G3_LOAD(xa0, xa1, xa2, xa3, xa4, xa5, xa6, xa7, jq + 4 * (i + 1));
          G3_STEP(xb0, xb1, xb2, xb3, xb4, xb5, xb6, xb7, jq + 4 * i);
        }
        if (i < nl) {
          G3_LOAD(xb0, xb1, xb2, xb3, xb4, xb5, xb6, xb7, jq + 4 * i);
          G3_STEP(xa0, xa1, xa2, xa3, xa4, xa5, xa6, xa7, jq + 4 * (i - 1));
          G3_STEP(xb0, xb1, xb2, xb3, xb4, xb5, xb6, xb7, jq + 4 * i);
        } else {
          G3_STEP(xa0, xa1, xa2, xa3, xa4, xa5, xa6, xa7, jq + 4 * (nl - 1));
        }
        if (jq == 3) {  // bias block
          s16x8 als = *(const s16x8*)&LSB[lsb][c][kg * 8];
          f32x4 Pb = MFMA(als, wbias, zf);
#pragma unroll
          for (int q = 0; q < 4; ++q) acc[q] += Pb[q];
        }
#pragma unroll
        for (int q = 0; q < 4; ++q) part[jq][kg * 4 + q][nt * 16 + c] = acc[q];
      }
      __syncthreads();

      // ---- Heun epilogue (thread owns element (r, t*32+hh)) + y exchange
      {
        int r = tid >> 5, hh = tid & 31;
        float raw = part[0][r][hh] + part[1][r][hh] + part[2][r][hh] + part[3][r][hh];
        u16 yb16;
        if (sub == 0) {
          yp_st = y_st + 0.5f * raw;
          yb16 = bf16u(y_st + raw);
        } else {
          y_st = yp_st + 0.5f * raw;
          yb16 = bf16u(y_st);
        }
        unsigned vv = yb16;
        unsigned up = (unsigned)__shfl_down((int)vv, 1);
        if ((hh & 1) == 0) {
          unsigned packed = vv | (up << 16);
          unsigned off = (unsigned)((phase & 1) * 65536 + g * 1024 + t * 256 + (tid >> 1));
          __hip_atomic_store(&ybuf[off], packed, __ATOMIC_RELAXED, __HIP_MEMORY_SCOPE_AGENT);
        }
      }
      __syncthreads();  // drains stores (vmcnt) before the arrival add
      if (tid == 0) __hip_atomic_fetch_add(ctrg, 1u, __ATOMIC_RELAXED, __HIP_MEMORY_SCOPE_AGENT);
      {
        unsigned tgt = 4u * (unsigned)(phase + 1);
        for (int sp = 0; sp < 20000; ++sp)
          if (__hip_atomic_load(ctrg, __ATOMIC_RELAXED, __HIP_MEMORY_SCOPE_AGENT) >= tgt) break;
      }
      asm volatile("" ::: "memory");
      {  // rebuild full YB from the 4 quarters
        const unsigned* srcb = ybuf + (phase & 1) * 65536 + g * 1024;
        for (int e2 = tid; e2 < 1024; e2 += 512) {
          unsigned pv = __hip_atomic_load(&srcb[e2], __ATOMIC_RELAXED, __HIP_MEMORY_SCOPE_AGENT);
          int tp = e2 >> 8, rem = e2 & 255;
          int rr = rem >> 4, cc2 = (rem & 15) << 1;
          YB[rr][tp * 32 + cc2]     = (u16)(pv & 0xffffu);
          YB[rr][tp * 32 + cc2 + 1] = (u16)(pv >> 16);
        }
      }
      __syncthreads();
      ++phase;
    }
  }

  // ---- logits + softmax from final bf16 y (t==0 only writes out)
  if (t == 0) {
    if (tid < 160) {
      int r = tid / 10, cc = tid % 10;
      float a = b2[cc];
#pragma unroll 4
      for (int h = 0; h < H; ++h) a += b2f(YB[r][h]) * W2[cc * H + h];
      LG[r][cc] = a;
    }
    __syncthreads();
    if (tid < 16) {
      float m = -1e30f;
#pragma unroll
      for (int cc = 0; cc < 10; ++cc) m = fmaxf(m, LG[tid][cc]);
      float ex[10]; float s = 0.f;
#pragma unroll
      for (int cc = 0; cc < 10; ++cc) { ex[cc] = expf(LG[tid][cc] - m); s += ex[cc]; }
      float inv = 1.f / s;
#pragma unroll
      for (int cc = 0; cc < 10; ++cc) out[(b0 + tid) * 10 + cc] = ex[cc] * inv;
    }
  }
}

extern "C" void kernel_launch(void* const* d_in, const int* in_sizes, int n_in,
                              void* d_out, int out_size, void* d_ws, size_t ws_size,
                              hipStream_t stream) {
  (void)in_sizes; (void)n_in; (void)out_size; (void)ws_size;
  const float* logsig = (const float*)d_in[1];
  const float* x0     = (const float*)d_in[2];
  const float* Wvf1   = (const float*)d_in[3];
  const float* bvf1   = (const float*)d_in[4];
  const float* Wvf2   = (const float*)d_in[5];
  const float* bvf2   = (const float*)d_in[6];
  const float* Wm     = (const float*)d_in[7];
  const float* bmv    = (const float*)d_in[8];
  const float* W1     = (const float*)d_in[9];
  const float* b1     = (const float*)d_in[10];
  const float* W2     = (const float*)d_in[11];
  const float* b2     = (const float*)d_in[12];
  u16* ws = (u16*)d_ws;
  unsigned* ctr  = (unsigned*)((char*)d_ws + (size_t)WS_TOTAL * 2);
  unsigned* ybuf = (unsigned*)((char*)d_ws + (size_t)WS_TOTAL * 2 + 4096);

  prep_weights<<<(WS_TOTAL + 255) / 256, 256, 0, stream>>>(Wvf1, Wvf2, Wm, bmv, ws);
  rde_main<<<NWG, 512, 0, stream>>>(logsig, x0, W1, b1, bvf1, bvf2, W2, b2, ws,
                                    ctr, ybuf, (float*)d_out);
}